// Round 12
// baseline (2995.462 us; speedup 1.0000x reference)
//
#include <hip/hip_runtime.h>
#include <hip/hip_fp16.h>

// Persistent fused GRU + value head, MI355X (gfx950).
// T=512,B=256,I=64,H=512. R12 = R11 (transaction-count collapse) with two fixes:
//   (1) Wih f16 scratch is PER-WAVE (R11 had all 4 waves clobbering one region
//       -> absmax 0.42); (2) __launch_bounds__(256,1) so the allocator may use
//       the full 512-VGPR budget (R11's single-arg form caps at 256 -> spills).
// Structure: 64 blocks = 16 batch groups x 4 slices (128 units). 4 waves/block,
// Whh stationary in VGPRs (~440/wave, 1 wave/SIMD). Group h-slab (16KB) loaded
// ONCE per block cooperatively into an LDS ping-pong -> ~131k -> ~10k MALL
// transactions/step vs R7. Fan-in 4 flags. Biases folded into the MFMA via
// K-extension (LDS col 512 = 1.0). Sync = R7-proven flags + drain (agent scope,
// MALL, replay-safe; flags memset each launch; hbuf reads gated by flags).

#define T_  512
#define B_  256
#define I_  64
#define H_  512
#define NBG 16
#define NJ  4                  // slice blocks per group
#define BT  16                 // batch rows per group
#define BLOCK 256
#define NSL 16                 // value-head slices (j,wv)
#define FLAG_STRIDE 32         // dwords: 128 B between flag words
#define LP  544                // LDS row pitch in halves (1088 B, 16B-aligned)

typedef _Float16 f16;
typedef _Float16 f16x4 __attribute__((ext_vector_type(4)));
typedef _Float16 f16x8 __attribute__((ext_vector_type(8)));
typedef float    f32x4 __attribute__((ext_vector_type(4)));
typedef unsigned int u32x2 __attribute__((ext_vector_type(2)));

__device__ __forceinline__ float sigmoid_f(float x) { return 1.f / (1.f + __expf(-x)); }
__device__ __forceinline__ float tanh_f(float x) {
    float e2 = __expf(2.f * x);
    return 1.f - 2.f / (e2 + 1.f);
}

__global__ __launch_bounds__(BLOCK, 1) void gru_persistent(
    const float* __restrict__ X, const float* __restrict__ Wih,
    const float* __restrict__ Whh, const float* __restrict__ bih,
    const float* __restrict__ bhh, const float* __restrict__ vw,
    const float* __restrict__ bias, float* __restrict__ Vout,
    f16* __restrict__ hbuf, unsigned int* __restrict__ flags,
    f16* __restrict__ wbuf, float* __restrict__ part, const int use_part)
{
    const int blk  = blockIdx.x;
    const int g    = blk & 15;            // batch group
    const int j    = blk >> 4;            // slice 0..3 (128 units each)
    const int b0   = g * BT;
    const int tid  = threadIdx.x;
    const int wv   = tid >> 6;            // wave: 32 units (2 M-tiles)
    const int lane = tid & 63;
    const int quad = lane >> 4;
    const int mrow = lane & 15;

    __shared__ __align__(16) f16 sh[2][BT][LP];   // h ping-pong + bias col @512

    // ---- stationary Whh A-fragments + bias K-extension (kt=16) ----
    // A[m=lane&15 -> unit][k=quad*8+e]; D: row=quad*4+r -> unit, col=lane&15 -> batch
    f16x8 wh[3][2][17];
    #pragma unroll
    for (int g3 = 0; g3 < 3; g3++) {
        #pragma unroll
        for (int tt = 0; tt < 2; tt++) {
            const int um = j * 128 + wv * 32 + tt * 16 + mrow;
            const float* wr = Whh + (size_t)(g3 * H_ + um) * H_;
            #pragma unroll
            for (int kt = 0; kt < 16; kt++) {
                const float* src = wr + kt * 32 + quad * 8;
                f16x8 f;
                #pragma unroll
                for (int e = 0; e < 8; e++) f[e] = (f16)src[e];
                wh[g3][tt][kt] = f;
            }
            const float bv = (g3 == 0) ? bih[um] + bhh[um]
                           : (g3 == 1) ? bih[H_ + um] + bhh[H_ + um]
                                       : bhh[2 * H_ + um];
            f16x8 fb;
            #pragma unroll
            for (int e = 0; e < 8; e++) fb[e] = (f16)0.f;
            if (quad == 0) fb[0] = (f16)bv;
            wh[g3][tt][16] = fb;
        }
    }
    float vw4[2][4];
    #pragma unroll
    for (int tt = 0; tt < 2; tt++)
        #pragma unroll
        for (int r = 0; r < 4; r++)
            vw4[tt][r] = vw[j * 128 + wv * 32 + tt * 16 + quad * 4 + r];

    // ---- pre-convert own Wih fragments to f16 scratch (PER-WAVE region) ----
    f16* wb = wbuf + ((size_t)blk * 4 + wv) * 8192;
    #pragma unroll
    for (int g3 = 0; g3 < 3; g3++)
        #pragma unroll
        for (int tt = 0; tt < 2; tt++) {
            const int um = j * 128 + wv * 32 + tt * 16 + mrow;
            #pragma unroll
            for (int kt = 0; kt < 2; kt++) {
                const float* src = Wih + (size_t)(g3 * H_ + um) * I_ + kt * 32 + quad * 8;
                f16x8 f;
                #pragma unroll
                for (int e = 0; e < 8; e++) f[e] = (f16)src[e];
                *(f16x8*)(wb + (size_t)(((g3 * 2 + tt) * 2 + kt) * 512) + lane * 8) = f;
            }
        }
    #pragma unroll
    for (int tt = 0; tt < 2; tt++) {      // n-gate bih via x K-extension marker
        const int um = 2 * H_ + j * 128 + wv * 32 + tt * 16 + mrow;
        f16x8 f;
        #pragma unroll
        for (int e = 0; e < 8; e++) f[e] = (f16)0.f;
        if (quad == 0) f[0] = (f16)bih[um];
        *(f16x8*)(wb + (size_t)((12 + tt) * 512) + lane * 8) = f;
    }
    f16x8 bx2;                            // K-extension B marker (k=0 -> 1.0)
    #pragma unroll
    for (int e = 0; e < 8; e++) bx2[e] = (f16)0.f;
    if (quad == 0) bx2[0] = (f16)1.0f;

    // ---- LDS init: zero slot0; bias cols 512..543 both slots (col512 = 1.0) ----
    {
        f16* p = &sh[0][0][0];
        for (int e = tid; e < BT * LP; e += BLOCK) p[e] = (f16)0.f;
    }
    for (int e = tid; e < 2 * BT * 32; e += BLOCK) {
        const int s = e >> 9, rem = e & 511, m = rem >> 5, c = rem & 31;
        sh[s][m][512 + c] = (c == 0) ? (f16)1.0f : (f16)0.f;
    }
    __syncthreads();

    unsigned int* gflags = flags + (size_t)g * (NJ * FLAG_STRIDE);
    unsigned int* myflag = gflags + j * FLAG_STRIDE;
    const float bias0 = bias[0];
    float hprev[2][4] = {{0.f,0.f,0.f,0.f},{0.f,0.f,0.f,0.f}};
    const int sl = j * 4 + wv;

    #pragma unroll 1
    for (int t = 0; t < T_; t++) {
        const int slotL = t & 1;
        // ---- X fragments early (HBM latency hides under poll/load) ----
        const float* xb = X + (size_t)t * (B_ * I_) + (size_t)(b0 + mrow) * I_ + quad * 8;
        const f32x4 xv0 = *(const f32x4*)xb;
        const f32x4 xv1 = *(const f32x4*)(xb + 4);
        const f32x4 xv2 = *(const f32x4*)(xb + 32);
        const f32x4 xv3 = *(const f32x4*)(xb + 36);
        f16x8 bx0, bx1;
        #pragma unroll
        for (int e = 0; e < 4; e++) {
            bx0[e] = (f16)xv0[e]; bx0[4 + e] = (f16)xv1[e];
            bx1[e] = (f16)xv2[e]; bx1[4 + e] = (f16)xv3[e];
        }

        if (t > 0) {
            // ---- 1. ballot poll of the 3 peer-block flags ----
            const unsigned target = (unsigned)t;
            for (;;) {
                unsigned v = target;
                if (lane < 3) {
                    const int jj = lane + (lane >= j ? 1 : 0);
                    const unsigned int* fp = gflags + jj * FLAG_STRIDE;
                    asm volatile("global_load_dword %0, %1, off sc0 sc1\n\t"
                                 "s_waitcnt vmcnt(0)"
                                 : "=v"(v) : "v"(fp) : "memory");
                }
                if (__ballot(v >= target) == ~0ull) break;
            }

            // ---- 2. cooperative slab load: 768 x 16B chunks over 256 lanes ----
            const f16* gb = hbuf + ((size_t)(slotL ^ 1) * NBG + g) * 8192;
            f16x8 cv0, cv1, cv2;
            int ms[3], us[3];
            const f16 *ga0, *ga1, *ga2;
            #pragma unroll
            for (int i = 0; i < 3; i++) {
                const int c = i * 256 + tid;
                const int sidx = c >> 6, local = c & 63;
                const int jjr = sidx >> 2, ww = sidx & 3;
                const int jj = jjr + (jjr >= j ? 1 : 0);
                const f16* ga = gb + (size_t)(jj * 4 + ww) * 512 + local * 8;
                if (i == 0) ga0 = ga; else if (i == 1) ga1 = ga; else ga2 = ga;
                ms[i] = (local << 1) & 15;
                us[i] = jj * 128 + ww * 32 + (local >> 5) * 16 + ((local >> 3) & 3) * 4;
            }
            asm volatile(
                "global_load_dwordx4 %0, %3, off sc0 sc1\n\t"
                "global_load_dwordx4 %1, %4, off sc0 sc1\n\t"
                "global_load_dwordx4 %2, %5, off sc0 sc1\n\t"
                "s_waitcnt vmcnt(0)"
                : "=&v"(cv0), "=&v"(cv1), "=&v"(cv2)
                : "v"(ga0), "v"(ga1), "v"(ga2)
                : "memory");
            #pragma unroll
            for (int i = 0; i < 3; i++) {
                const f16x8 cv = (i == 0) ? cv0 : (i == 1) ? cv1 : cv2;
                f16x4 lo = __builtin_shufflevector(cv, cv, 0, 1, 2, 3);
                f16x4 hi = __builtin_shufflevector(cv, cv, 4, 5, 6, 7);
                *(f16x4*)&sh[slotL][ms[i]][us[i]]     = lo;
                *(f16x4*)&sh[slotL][ms[i] + 1][us[i]] = hi;
            }
        }
        __syncthreads();   // slab (remote + own-from-last-step) ready in LDS

        // ---- 3. x-projections (Wih frags stream from per-wave L1 scratch) ----
        f32x4 a_r[2], a_z[2], a_ni[2], a_nh[2];
        const f32x4 zero = {0.f, 0.f, 0.f, 0.f};
        #pragma unroll
        for (int tt = 0; tt < 2; tt++) {
            f16x8 w00 = *(const f16x8*)(wb + (size_t)(((0*2+tt)*2+0)*512) + lane*8);
            f16x8 w01 = *(const f16x8*)(wb + (size_t)(((0*2+tt)*2+1)*512) + lane*8);
            f16x8 w10 = *(const f16x8*)(wb + (size_t)(((1*2+tt)*2+0)*512) + lane*8);
            f16x8 w11 = *(const f16x8*)(wb + (size_t)(((1*2+tt)*2+1)*512) + lane*8);
            f16x8 w20 = *(const f16x8*)(wb + (size_t)(((2*2+tt)*2+0)*512) + lane*8);
            f16x8 w21 = *(const f16x8*)(wb + (size_t)(((2*2+tt)*2+1)*512) + lane*8);
            f16x8 wnx = *(const f16x8*)(wb + (size_t)((12+tt)*512) + lane*8);
            a_r[tt]  = __builtin_amdgcn_mfma_f32_16x16x32_f16(w00, bx0, zero,     0,0,0);
            a_r[tt]  = __builtin_amdgcn_mfma_f32_16x16x32_f16(w01, bx1, a_r[tt],  0,0,0);
            a_z[tt]  = __builtin_amdgcn_mfma_f32_16x16x32_f16(w10, bx0, zero,     0,0,0);
            a_z[tt]  = __builtin_amdgcn_mfma_f32_16x16x32_f16(w11, bx1, a_z[tt],  0,0,0);
            a_ni[tt] = __builtin_amdgcn_mfma_f32_16x16x32_f16(w20, bx0, zero,     0,0,0);
            a_ni[tt] = __builtin_amdgcn_mfma_f32_16x16x32_f16(w21, bx1, a_ni[tt], 0,0,0);
            a_ni[tt] = __builtin_amdgcn_mfma_f32_16x16x32_f16(wnx, bx2, a_ni[tt], 0,0,0);
            a_nh[tt] = zero;
        }

        // ---- 4. h-MFMAs from LDS (kt16 = bias extension, col512 = 1.0) ----
        #pragma unroll
        for (int kt = 0; kt < 17; kt++) {
            const f16x8 hb = *(const f16x8*)&sh[slotL][mrow][kt * 32 + quad * 8];
            #pragma unroll
            for (int tt = 0; tt < 2; tt++) {
                a_r[tt]  = __builtin_amdgcn_mfma_f32_16x16x32_f16(wh[0][tt][kt], hb, a_r[tt],  0,0,0);
                a_z[tt]  = __builtin_amdgcn_mfma_f32_16x16x32_f16(wh[1][tt][kt], hb, a_z[tt],  0,0,0);
                a_nh[tt] = __builtin_amdgcn_mfma_f32_16x16x32_f16(wh[2][tt][kt], hb, a_nh[tt], 0,0,0);
            }
        }

        // ---- 5. gates in registers; LDS own-write; one coalesced global store ----
        const int slotN = slotL ^ 1;
        float hnf[2][4];
        union { f16 h[4]; u32x2 v; f16x4 h4; } pk[2];
        #pragma unroll
        for (int tt = 0; tt < 2; tt++) {
            #pragma unroll
            for (int r = 0; r < 4; r++) {
                const float rg = sigmoid_f(a_r[tt][r]);
                const float zg = sigmoid_f(a_z[tt][r]);
                const float ng = tanh_f(a_ni[tt][r] + rg * a_nh[tt][r]);
                const float hn = (1.f - zg) * ng + zg * hprev[tt][r];
                hprev[tt][r] = hn;
                hnf[tt][r] = hn;
                pk[tt].h[r] = (f16)hn;
            }
            *(f16x4*)&sh[slotN][mrow][j * 128 + wv * 32 + tt * 16 + quad * 4] = pk[tt].h4;
        }
        {
            f16* stb = hbuf + ((size_t)slotL * NBG + g) * 8192
                     + (size_t)(j * 4 + wv) * 512 + quad * 64 + mrow * 4;
            asm volatile(
                "global_store_dwordx2 %0, %1, off sc0 sc1\n\t"
                "global_store_dwordx2 %0, %2, off offset:512 sc0 sc1\n\t"
                "s_waitcnt vmcnt(0)"
                :: "v"(stb), "v"(pk[0].v), "v"(pk[1].v) : "memory");
        }
        __syncthreads();   // all 4 waves' stores drained (+ LDS own-writes ordered)
        if (tid == 0) {
            const unsigned fv = (unsigned)(t + 1);
            asm volatile("global_store_dword %0, %1, off sc0 sc1"
                         :: "v"(myflag), "v"(fv) : "memory");
        }

        // ---- 6. value head (off critical path) ----
        float s = hnf[0][0] * vw4[0][0] + hnf[0][1] * vw4[0][1]
                + hnf[0][2] * vw4[0][2] + hnf[0][3] * vw4[0][3]
                + hnf[1][0] * vw4[1][0] + hnf[1][1] * vw4[1][1]
                + hnf[1][2] * vw4[1][2] + hnf[1][3] * vw4[1][3];
        s += __shfl_xor(s, 16);
        s += __shfl_xor(s, 32);
        if (quad == 0) {
            if (use_part) part[(size_t)sl * (T_ * B_) + (size_t)t * B_ + b0 + mrow] = s;
            else atomicAdd(&Vout[(size_t)t * B_ + b0 + mrow], s + (sl == 0 ? bias0 : 0.f));
        }
    }
}

__global__ __launch_bounds__(256) void value_reduce(
    const float* __restrict__ part, const float* __restrict__ bias,
    float* __restrict__ Vout)
{
    const int i = blockIdx.x * 256 + threadIdx.x;   // i < T_*B_
    float s = bias[0];
    #pragma unroll
    for (int sl = 0; sl < NSL; sl++) s += part[(size_t)sl * (T_ * B_) + i];
    Vout[i] = s;
}

extern "C" void kernel_launch(void* const* d_in, const int* in_sizes, int n_in,
                              void* d_out, int out_size, void* d_ws, size_t ws_size,
                              hipStream_t stream) {
    const float* X    = (const float*)d_in[0];
    const float* Wih  = (const float*)d_in[1];
    const float* Whh  = (const float*)d_in[2];
    const float* bih  = (const float*)d_in[3];
    const float* bhh  = (const float*)d_in[4];
    const float* vw   = (const float*)d_in[5];
    const float* bias = (const float*)d_in[6];
    float* Vout = (float*)d_out;

    f16* hbuf = (f16*)d_ws;                                          // 512 KB, no init
    const size_t hbytes    = (size_t)2 * NBG * 8192 * sizeof(f16);
    const size_t flagbytes = (size_t)NBG * NJ * FLAG_STRIDE * sizeof(unsigned);  // 8 KB
    unsigned int* flags = (unsigned int*)((char*)d_ws + hbytes);
    f16* wbuf = (f16*)((char*)d_ws + hbytes + flagbytes);            // 4 MB, per-wave regions
    const size_t wbytes = (size_t)256 * 8192 * sizeof(f16);
    float* part = (float*)((char*)d_ws + hbytes + flagbytes + wbytes);
    const size_t partbytes = (size_t)NSL * T_ * B_ * sizeof(float);  // 8.4 MB
    const int use_part = (ws_size >= hbytes + flagbytes + wbytes + partbytes) ? 1 : 0;

    hipMemsetAsync(flags, 0, flagbytes, stream);
    if (!use_part)
        hipMemsetAsync(d_out, 0, (size_t)out_size * sizeof(float), stream);

    gru_persistent<<<64, BLOCK, 0, stream>>>(X, Wih, Whh, bih, bhh, vw, bias,
                                             Vout, hbuf, flags, wbuf, part, use_part);
    if (use_part)
        value_reduce<<<(T_ * B_) / 256, 256, 0, stream>>>(part, bias, Vout);
}

// Round 13
// 1409.516 us; speedup vs baseline: 2.1252x; 2.1252x over previous
//
#include <hip/hip_runtime.h>
#include <hip/hip_fp16.h>

// Persistent fused GRU + value head, MI355X (gfx950).
// T=512,B=256,I=64,H=512. 256 blocks = 16 batch groups x 16 hidden slices.
// R13 = R7 (champion: flag ballot sync, direct h loads, weights=A operand swap,
// service wave for X) + two transaction cuts:
//   (1) each group's 32 flags packed into ONE 128B line (lane i reads dword i
//       -> poll = 1 coalesced line read instead of 32 line reads);
//   (2) h slab stored fragment-major (idx = (u>>3)*128 + m*8 + (u&7)) so each
//       of the consumer's 16 loads covers 1KB contiguous (full 128B lines).
// All cross-block state agent-scope at the MALL (sc0 sc1) — replay-safe.

#define T_  512
#define B_  256
#define I_  64
#define H_  512
#define NBG 16
#define BT  16                  // batch rows per group
#define HS  32                  // hidden units per block
#define BLOCK 192
#define NSL 32                  // value-head slices (j,wv)

typedef _Float16 f16;
typedef _Float16 f16x8 __attribute__((ext_vector_type(8)));
typedef float    f32x4 __attribute__((ext_vector_type(4)));
typedef unsigned int u32x2 __attribute__((ext_vector_type(2)));

__device__ __forceinline__ float sigmoid_f(float x) { return 1.f / (1.f + __expf(-x)); }
__device__ __forceinline__ float tanh_f(float x) {
    float e2 = __expf(2.f * x);
    return 1.f - 2.f / (e2 + 1.f);
}

__global__ __launch_bounds__(BLOCK, 1) void gru_persistent(
    const float* __restrict__ X, const float* __restrict__ Wih,
    const float* __restrict__ Whh, const float* __restrict__ bih,
    const float* __restrict__ bhh, const float* __restrict__ vw,
    const float* __restrict__ bias, float* __restrict__ Vout,
    f16* __restrict__ hbuf, unsigned int* __restrict__ flags,
    float* __restrict__ part, const int use_part)
{
    const int blk  = blockIdx.x;
    const int g    = (blk & 7) * 2 + (blk >> 7);   // group members share blk%8
    const int j    = (blk >> 3) & 15;
    const int b0   = g * BT;
    const int tid  = threadIdx.x;
    const int wv   = tid >> 6;
    const int lane = tid & 63;
    const int quad = lane >> 4;
    const int mrow = lane & 15;

    __shared__ __align__(16) f16 sh_x[2][BT][I_ + 8];   // X_t ping-pong (f16), padded
    unsigned int* gflags = flags + (size_t)g * 32;       // one 128B line per group

    if (wv < 2) {
        // ============ MFMA waves: weights=A (units on M), h/x=B (batch on N) ============
        // A[m=lane&15 -> unit][k=quad*8+e]; D: row=quad*4+r -> unit, col=lane&15 -> batch
        f16x8 wh[3][16];
        f16x8 wxA[3][2];
        const int um = HS * j + wv * 16 + mrow;
        #pragma unroll
        for (int g3 = 0; g3 < 3; g3++) {
            const size_t grow = (size_t)(g3 * H_ + um);
            #pragma unroll
            for (int kt = 0; kt < 16; kt++) {
                const float* src = Whh + grow * H_ + kt * 32 + quad * 8;
                #pragma unroll
                for (int e = 0; e < 8; e++) wh[g3][kt][e] = (f16)src[e];
            }
            #pragma unroll
            for (int kt = 0; kt < 2; kt++) {
                const float* src = Wih + grow * I_ + kt * 32 + quad * 8;
                #pragma unroll
                for (int e = 0; e < 8; e++) wxA[g3][kt][e] = (f16)src[e];
            }
        }
        float b_r4[4], b_z4[4], b_ni4[4], b_nh4[4], vw4[4];
        #pragma unroll
        for (int r = 0; r < 4; r++) {
            const int ub = HS * j + wv * 16 + quad * 4 + r;
            b_r4[r]  = bih[ub] + bhh[ub];
            b_z4[r]  = bih[H_ + ub] + bhh[H_ + ub];
            b_ni4[r] = bih[2 * H_ + ub];
            b_nh4[r] = bhh[2 * H_ + ub];
            vw4[r]   = vw[ub];
        }
        float hprev[4] = {0.f, 0.f, 0.f, 0.f};   // fp32 anchor for z*h (t=0 zeros)
        unsigned int* myflag = gflags + (j * 2 + wv);
        const int sl = j * 2 + wv;
        const float bias0 = bias[0];

        __syncthreads();   // init: service staged X_0 into slot 0

        #pragma unroll 1
        for (int t = 0; t < T_; t++) {
            // ---- 1. ballot poll: one coalesced 128B line read per iteration ----
            if (t > 0) {
                const unsigned target = (unsigned)t;
                for (;;) {
                    unsigned v = target;
                    if (lane < 32) {
                        const unsigned int* fp = gflags + lane;
                        asm volatile("global_load_dword %0, %1, off sc0 sc1\n\t"
                                     "s_waitcnt vmcnt(0)"
                                     : "=v"(v) : "v"(fp) : "memory");
                    }
                    if (__ballot(v >= target) == ~0ull) break;
                }
            }

            // ---- 2. h_{t-1} fragments: fragment-major slab, 16 x 1KB-contiguous loads ----
            f16x8 afr[16];
            const char* pb = (const char*)(hbuf
                           + ((size_t)((t & 1) ^ 1) * NBG + g) * 8192)
                           + quad * 256 + mrow * 16;
            asm volatile(
                "global_load_dwordx4 %0, %16, off sc0 sc1\n\t"
                "global_load_dwordx4 %1, %16, off offset:1024 sc0 sc1\n\t"
                "global_load_dwordx4 %2, %16, off offset:2048 sc0 sc1\n\t"
                "global_load_dwordx4 %3, %16, off offset:3072 sc0 sc1\n\t"
                "global_load_dwordx4 %4, %17, off sc0 sc1\n\t"
                "global_load_dwordx4 %5, %17, off offset:1024 sc0 sc1\n\t"
                "global_load_dwordx4 %6, %17, off offset:2048 sc0 sc1\n\t"
                "global_load_dwordx4 %7, %17, off offset:3072 sc0 sc1\n\t"
                "global_load_dwordx4 %8, %18, off sc0 sc1\n\t"
                "global_load_dwordx4 %9, %18, off offset:1024 sc0 sc1\n\t"
                "global_load_dwordx4 %10, %18, off offset:2048 sc0 sc1\n\t"
                "global_load_dwordx4 %11, %18, off offset:3072 sc0 sc1\n\t"
                "global_load_dwordx4 %12, %19, off sc0 sc1\n\t"
                "global_load_dwordx4 %13, %19, off offset:1024 sc0 sc1\n\t"
                "global_load_dwordx4 %14, %19, off offset:2048 sc0 sc1\n\t"
                "global_load_dwordx4 %15, %19, off offset:3072 sc0 sc1\n\t"
                "s_waitcnt vmcnt(0)"
                : "=&v"(afr[0]), "=&v"(afr[1]), "=&v"(afr[2]), "=&v"(afr[3]),
                  "=&v"(afr[4]), "=&v"(afr[5]), "=&v"(afr[6]), "=&v"(afr[7]),
                  "=&v"(afr[8]), "=&v"(afr[9]), "=&v"(afr[10]), "=&v"(afr[11]),
                  "=&v"(afr[12]), "=&v"(afr[13]), "=&v"(afr[14]), "=&v"(afr[15])
                : "v"(pb), "v"(pb + 4096), "v"(pb + 8192), "v"(pb + 12288)
                : "memory");

            // ---- 3. MFMA: 48 h-MFMAs + 6 x-MFMAs ----
            f16x8 bx0 = *(const f16x8*)&sh_x[t & 1][mrow][quad * 8];
            f16x8 bx1 = *(const f16x8*)&sh_x[t & 1][mrow][32 + quad * 8];
            const f32x4 zero = {0.f, 0.f, 0.f, 0.f};
            f32x4 a_r  = __builtin_amdgcn_mfma_f32_16x16x32_f16(wxA[0][0], bx0, zero, 0, 0, 0);
            f32x4 a_z  = __builtin_amdgcn_mfma_f32_16x16x32_f16(wxA[1][0], bx0, zero, 0, 0, 0);
            f32x4 a_ni = __builtin_amdgcn_mfma_f32_16x16x32_f16(wxA[2][0], bx0, zero, 0, 0, 0);
            a_r  = __builtin_amdgcn_mfma_f32_16x16x32_f16(wxA[0][1], bx1, a_r,  0, 0, 0);
            a_z  = __builtin_amdgcn_mfma_f32_16x16x32_f16(wxA[1][1], bx1, a_z,  0, 0, 0);
            a_ni = __builtin_amdgcn_mfma_f32_16x16x32_f16(wxA[2][1], bx1, a_ni, 0, 0, 0);
            f32x4 a_nh = zero;
            #pragma unroll
            for (int kt = 0; kt < 16; kt++) {
                a_r  = __builtin_amdgcn_mfma_f32_16x16x32_f16(wh[0][kt], afr[kt], a_r,  0, 0, 0);
                a_z  = __builtin_amdgcn_mfma_f32_16x16x32_f16(wh[1][kt], afr[kt], a_z,  0, 0, 0);
                a_nh = __builtin_amdgcn_mfma_f32_16x16x32_f16(wh[2][kt], afr[kt], a_nh, 0, 0, 0);
            }

            // ---- 4. gates in registers; one 8B fragment-major h-store/lane ----
            float hn[4];
            union { f16 h[4]; u32x2 v; } pk;
            #pragma unroll
            for (int r = 0; r < 4; r++) {
                float rg = sigmoid_f(a_r[r] + b_r4[r]);
                float zg = sigmoid_f(a_z[r] + b_z4[r]);
                float ng = tanh_f(a_ni[r] + b_ni4[r] + rg * (a_nh[r] + b_nh4[r]));
                hn[r] = (1.f - zg) * ng + zg * hprev[r];
                hprev[r] = hn[r];
                pk.h[r] = (f16)hn[r];
            }
            {
                // h[batch=mrow][u=32j+16wv+4quad+r] -> idx=(u>>3)*128 + mrow*8 + (u&7)
                f16* hp = hbuf + ((size_t)(t & 1) * NBG + g) * 8192
                        + (size_t)((4 * j + 2 * wv + (quad >> 1)) * 128
                                   + mrow * 8 + (quad & 1) * 4);
                asm volatile("global_store_dwordx2 %0, %1, off sc0 sc1"
                             :: "v"(hp), "v"(pk.v) : "memory");
            }
            // value-head partial overlaps the store's flight time
            float s = hn[0] * vw4[0] + hn[1] * vw4[1] + hn[2] * vw4[2] + hn[3] * vw4[3];
            s += __shfl_xor(s, 16);
            s += __shfl_xor(s, 32);

            asm volatile("s_waitcnt vmcnt(0)" ::: "memory");   // h at MALL before flag
            if (lane == 0)
                __hip_atomic_store(myflag, (unsigned)(t + 1),
                                   __ATOMIC_RELAXED, __HIP_MEMORY_SCOPE_AGENT);
            if (quad == 0) {
                if (use_part) part[(size_t)sl * (T_ * B_) + (size_t)t * B_ + b0 + mrow] = s;
                else atomicAdd(&Vout[(size_t)t * B_ + b0 + mrow], s + (sl == 0 ? bias0 : 0.f));
            }
            __syncthreads();   // X ping-pong fence with service wave (off exchange path)
        }
    } else {
        // ============== service wave: X_{t+1} -> LDS ping-pong (off-path) ==============
        const int bb = lane >> 2, seg = (lane & 3) * 16;
        {   // stage X_0 -> slot 0
            const float* xs = X + (size_t)(b0 + bb) * I_ + seg;
            const float4 x0 = *(const float4*)(xs + 0),  x1 = *(const float4*)(xs + 4);
            const float4 x2 = *(const float4*)(xs + 8),  x3 = *(const float4*)(xs + 12);
            f16* dst = &sh_x[0][bb][seg];
            f16x8 p0 = {(f16)x0.x,(f16)x0.y,(f16)x0.z,(f16)x0.w,(f16)x1.x,(f16)x1.y,(f16)x1.z,(f16)x1.w};
            f16x8 p1 = {(f16)x2.x,(f16)x2.y,(f16)x2.z,(f16)x2.w,(f16)x3.x,(f16)x3.y,(f16)x3.z,(f16)x3.w};
            *(f16x8*)dst = p0; *(f16x8*)(dst + 8) = p1;
        }
        __syncthreads();   // init barrier
        #pragma unroll 1
        for (int t = 0; t < T_; t++) {
            if (t + 1 < T_) {
                const float* xs = X + (size_t)(t + 1) * (B_ * I_) + (size_t)(b0 + bb) * I_ + seg;
                const float4 x0 = *(const float4*)(xs + 0),  x1 = *(const float4*)(xs + 4);
                const float4 x2 = *(const float4*)(xs + 8),  x3 = *(const float4*)(xs + 12);
                f16* dst = &sh_x[(t + 1) & 1][bb][seg];
                f16x8 p0 = {(f16)x0.x,(f16)x0.y,(f16)x0.z,(f16)x0.w,(f16)x1.x,(f16)x1.y,(f16)x1.z,(f16)x1.w};
                f16x8 p1 = {(f16)x2.x,(f16)x2.y,(f16)x2.z,(f16)x2.w,(f16)x3.x,(f16)x3.y,(f16)x3.z,(f16)x3.w};
                *(f16x8*)dst = p0; *(f16x8*)(dst + 8) = p1;
            }
            __syncthreads();
        }
    }
}

__global__ __launch_bounds__(256) void value_reduce(
    const float* __restrict__ part, const float* __restrict__ bias,
    float* __restrict__ Vout)
{
    const int i = blockIdx.x * 256 + threadIdx.x;   // i < T_*B_
    float s = bias[0];
    #pragma unroll
    for (int sl = 0; sl < NSL; sl++) s += part[(size_t)sl * (T_ * B_) + i];
    Vout[i] = s;
}

extern "C" void kernel_launch(void* const* d_in, const int* in_sizes, int n_in,
                              void* d_out, int out_size, void* d_ws, size_t ws_size,
                              hipStream_t stream) {
    const float* X    = (const float*)d_in[0];
    const float* Wih  = (const float*)d_in[1];
    const float* Whh  = (const float*)d_in[2];
    const float* bih  = (const float*)d_in[3];
    const float* bhh  = (const float*)d_in[4];
    const float* vw   = (const float*)d_in[5];
    const float* bias = (const float*)d_in[6];
    float* Vout = (float*)d_out;

    f16* hbuf = (f16*)d_ws;
    const size_t hbytes    = (size_t)2 * B_ * H_ * sizeof(f16);        // 512 KB
    const size_t flagbytes = (size_t)NBG * 32 * sizeof(unsigned);      // 2 KB (1 line/group)
    unsigned int* flags = (unsigned int*)((char*)d_ws + hbytes);
    float* part = (float*)((char*)d_ws + hbytes + flagbytes);
    const size_t partbytes = (size_t)NSL * T_ * B_ * sizeof(float);    // 16.8 MB
    const int use_part = (ws_size >= hbytes + flagbytes + partbytes) ? 1 : 0;

    hipMemsetAsync(d_ws, 0, hbytes + flagbytes, stream);   // hbuf zeros (t=0) + flags
    if (!use_part)
        hipMemsetAsync(d_out, 0, (size_t)out_size * sizeof(float), stream);

    gru_persistent<<<256, BLOCK, 0, stream>>>(X, Wih, Whh, bih, bhh, vw, bias,
                                              Vout, hbuf, flags, part, use_part);
    if (use_part)
        value_reduce<<<(T_ * B_) / 256, 256, 0, stream>>>(part, bias, Vout);
}